// Round 8
// baseline (357.888 us; speedup 1.0000x reference)
//
#include <hip/hip_runtime.h>

typedef unsigned short u16;
typedef __attribute__((ext_vector_type(8))) short short8;
typedef __attribute__((ext_vector_type(4))) float f32x4;

#define N_INST 2000
#define H_DIM 256
#define D_DIM 64
#define R_DIM 49
#define LN_EPS 1e-5f
#define SPLITK 14

__device__ __forceinline__ u16 f2bf(float f) {
  union { float f; unsigned int i; } x; x.f = f;
  unsigned int r = x.i + 0x7fffu + ((x.i >> 16) & 1u);  // RNE
  return (u16)(r >> 16);
}
__device__ __forceinline__ float bf2f(u16 u) {
  union { unsigned int i; float f; } x; x.i = ((unsigned int)u) << 16; return x.f;
}
__device__ __forceinline__ short8 ld8(const u16* p) {
  return *reinterpret_cast<const short8*>(p);
}
__device__ __forceinline__ short8 pack8(float4 a, float4 b) {
  short8 r;
  r[0] = (short)f2bf(a.x); r[1] = (short)f2bf(a.y);
  r[2] = (short)f2bf(a.z); r[3] = (short)f2bf(a.w);
  r[4] = (short)f2bf(b.x); r[5] = (short)f2bf(b.y);
  r[6] = (short)f2bf(b.z); r[7] = (short)f2bf(b.w);
  return r;
}
__device__ __forceinline__ f32x4 mfma16(short8 a, short8 b, f32x4 c) {
  return __builtin_amdgcn_mfma_f32_16x16x32_bf16(a, b, c, 0, 0, 0);
}
__device__ __forceinline__ void wave_reduce2(float& s, float& s2) {
#pragma unroll
  for (int off = 32; off > 0; off >>= 1) {
    s  += __shfl_down(s, off);
    s2 += __shfl_down(s2, off);
  }
  s = __shfl(s, 0); s2 = __shfl(s2, 0);
}
__device__ __forceinline__ void gload16(const u16* g, u16* l) {
  __builtin_amdgcn_global_load_lds(
      (const __attribute__((address_space(1))) void*)g,
      (__attribute__((address_space(3))) void*)l, 16, 0, 0);
}

// ---------------- cast/transpose prep kernels ----------------
__global__ __launch_bounds__(256) void cast_pro(const float* __restrict__ in,
                                                u16* __restrict__ out, int n4) {
  for (int i = blockIdx.x * 256 + threadIdx.x; i < n4; i += gridDim.x * 256) {
    float4 v = ((const float4*)in)[i];
    u16* op = out + i * 4;
    op[0] = f2bf(v.x); op[1] = f2bf(v.y); op[2] = f2bf(v.z); op[3] = f2bf(v.w);
  }
}

// Wdyn (256 x 32768) fp32 -> WdynT bf16, transposed + permuted (both halves):
//  half0: WdynT[d*256+h][k]      = Wdyn[k][h*64+d]          (p1 -> col d*256+h)
//  half1: WdynT[16384+h*64+d][k] = Wdyn[k][16384+d*256+h]   (p2 -> col 16384+h*64+d)
__global__ __launch_bounds__(256) void cast_wdyn(const float* __restrict__ W,
                                                 u16* __restrict__ WT) {
  __shared__ u16 T[64][65];
  const int tid = threadIdx.x;
  const int wave = tid >> 6, lane = tid & 63;
  const int half = blockIdx.x >> 10;
  const int b = blockIdx.x & 1023;
  const int kt = b >> 8;
  long colbase, rowbase; int rstride;
  if (half == 0) {
    int h = b & 255;
    colbase = (long)h * 64; rowbase = h; rstride = 256;
  } else {
    int d = b & 63, hc = (b >> 6) & 3;
    colbase = 16384L + d * 256 + hc * 64;
    rowbase = 16384L + hc * 4096 + d; rstride = 64;
  }
#pragma unroll
  for (int i = 0; i < 16; ++i) {
    int kk = wave * 16 + i;
    int k = kt * 64 + kk;
    T[kk][lane] = f2bf(W[(long)k * 32768 + colbase + lane]);
  }
  __syncthreads();
#pragma unroll
  for (int i = 0; i < 16; ++i) {
    int jj = wave * 16 + i;
    long ro = rowbase + (long)jj * rstride;
    WT[ro * 256 + kt * 64 + lane] = T[lane][jj];
  }
}

// Wout (12544 x 256) fp32 -> WoutT (256 x 12544) bf16
__global__ __launch_bounds__(256) void cast_wout(const float* __restrict__ W,
                                                 u16* __restrict__ WT) {
  __shared__ u16 T[64][65];
  const int tid = threadIdx.x;
  const int wave = tid >> 6, lane = tid & 63;
  const int kt = blockIdx.x >> 2, ct = blockIdx.x & 3;
#pragma unroll
  for (int i = 0; i < 16; ++i) {
    int kk = wave * 16 + i;
    long k = (long)kt * 64 + kk;
    T[kk][lane] = f2bf(W[k * 256 + ct * 64 + lane]);
  }
  __syncthreads();
#pragma unroll
  for (int i = 0; i < 16; ++i) {
    int cc = wave * 16 + i;
    long c = (long)ct * 64 + cc;
    WT[c * 12544 + (long)kt * 64 + lane] = T[lane][cc];
  }
}

// ---------------- 128x128 GEMM, double-buffered DMA staging ----------------
// cmode 1: bf16 store in MFMA-fragment-native P12 layout (+permuted bias).
// cmode 2: fp32 split-K partial at Cout + s*c_stride_s.
__global__ __launch_bounds__(256, 3) void gemm128(
    const u16* __restrict__ A, int lda, int M,
    const u16* __restrict__ BT, int ldbt,
    const float* __restrict__ bias,
    void* __restrict__ Cout, int ldc, long c_stride_s,
    int ksteps, int n_blocks, int cmode)
{
  union Smem {
    struct { u16 a[2][128 * 32]; u16 b[2][128 * 32]; } s;
    u16 cb[128 * 128];
  };
  __shared__ Smem sm;

  const int tid = threadIdx.x;
  const int wave = tid >> 6, lane = tid & 63;
  const int quad = lane >> 4, l16 = lane & 15;
  const int wm = wave >> 1, wn = wave & 1;
  const int bid = blockIdx.x;
  const int mblk = bid / n_blocks, nblk = bid - mblk * n_blocks;
  const int m0 = mblk * 128, n0 = nblk * 128;
  const int s = blockIdx.y;
  const int kb = s * ksteps * 32;

  const int cl = tid & 3;
  const int r0 = tid >> 2, r1 = 64 + (tid >> 2);
  const int cg0 = cl ^ ((r0 >> 1) & 3);
  const int cg1 = cl ^ ((r1 >> 1) & 3);
  int ga0 = m0 + r0; if (ga0 >= M) ga0 = M - 1;
  int ga1 = m0 + r1; if (ga1 >= M) ga1 = M - 1;
  const u16* gA0 = A + (long)ga0 * lda + kb + cg0 * 8;
  const u16* gA1 = A + (long)ga1 * lda + kb + cg1 * 8;
  const u16* gB0 = BT + (long)(n0 + r0) * ldbt + kb + cg0 * 8;
  const u16* gB1 = BT + (long)(n0 + r1) * ldbt + kb + cg1 * 8;

  int fAoff[4], fBoff[4];
#pragma unroll
  for (int i = 0; i < 4; ++i) {
    int rt = wm * 64 + i * 16 + l16;
    fAoff[i] = rt * 32 + (quad ^ ((rt >> 1) & 3)) * 8;
    int ct = wn * 64 + i * 16 + l16;
    fBoff[i] = ct * 32 + (quad ^ ((ct >> 1) & 3)) * 8;
  }

  f32x4 acc[4][4];
#pragma unroll
  for (int mi = 0; mi < 4; ++mi)
#pragma unroll
    for (int ni = 0; ni < 4; ++ni) acc[mi][ni] = f32x4{0.f, 0.f, 0.f, 0.f};

  gload16(gA0, &sm.s.a[0][tid * 8]);
  gload16(gA1, &sm.s.a[0][(tid + 256) * 8]);
  gload16(gB0, &sm.s.b[0][tid * 8]);
  gload16(gB1, &sm.s.b[0][(tid + 256) * 8]);

  for (int ks = 0; ks < ksteps; ++ks) {
    const int cur = ks & 1, nxt = cur ^ 1;
    __syncthreads();
    if (ks + 1 < ksteps) {
      const int ko = (ks + 1) * 32;
      gload16(gA0 + ko, &sm.s.a[nxt][tid * 8]);
      gload16(gA1 + ko, &sm.s.a[nxt][(tid + 256) * 8]);
      gload16(gB0 + ko, &sm.s.b[nxt][tid * 8]);
      gload16(gB1 + ko, &sm.s.b[nxt][(tid + 256) * 8]);
    }
    short8 av[4], bv[4];
#pragma unroll
    for (int i = 0; i < 4; ++i) {
      av[i] = ld8(&sm.s.a[cur][fAoff[i]]);
      bv[i] = ld8(&sm.s.b[cur][fBoff[i]]);
    }
#pragma unroll
    for (int mi = 0; mi < 4; ++mi)
#pragma unroll
      for (int ni = 0; ni < 4; ++ni)
        acc[mi][ni] = mfma16(av[mi], bv[ni], acc[mi][ni]);
  }

  if (cmode == 1) {
    float bvv[4];
#pragma unroll
    for (int ni = 0; ni < 4; ++ni) {
      int col = n0 + wn * 64 + ni * 16 + l16;
      int bi = (col < 16384) ? (((col & 255) << 6) + (col >> 8))
                             : (16384 + ((col & 63) << 8) + ((col >> 6) & 255));
      bvv[ni] = bias[bi];
    }
    __syncthreads();
#pragma unroll
    for (int mi = 0; mi < 4; ++mi)
#pragma unroll
      for (int ni = 0; ni < 4; ++ni)
#pragma unroll
        for (int i = 0; i < 4; ++i) {
          int row = wm * 64 + mi * 16 + quad * 4 + i;
          int col = wn * 64 + ni * 16 + l16;
          sm.cb[row * 128 + col] = f2bf(acc[mi][ni][i] + bvv[ni]);
        }
    __syncthreads();
    u16* Cp = (u16*)Cout;
#pragma unroll
    for (int j = 0; j < 8; ++j) {
      int lin = j * 2048 + tid * 8;
      int row = lin >> 7, col0 = n0 + (lin & 127);
      int grow = m0 + row;
      long toff;
      if (col0 < 16384) {
        int d = col0 >> 8, h = col0 & 255;
        toff = ((((d >> 4) * 8 + (h >> 5)) * 16 + (d & 15)) * 4 +
                ((h >> 3) & 3)) * 8;
      } else {
        int c2 = col0 - 16384;
        int h = c2 >> 6, d = c2 & 63;
        toff = 16384 + ((((h >> 4) * 2 + (d >> 5)) * 16 + (h & 15)) * 4 +
                        ((d >> 3) & 3)) * 8;
      }
      if (grow < M)
        *reinterpret_cast<short8*>(Cp + (long)grow * 32768 + toff) =
            ld8(&sm.cb[lin]);
    }
  } else {
    float* Cp = (float*)Cout + (long)s * c_stride_s;
#pragma unroll
    for (int mi = 0; mi < 4; ++mi)
#pragma unroll
      for (int ni = 0; ni < 4; ++ni) {
        int col = n0 + wn * 64 + ni * 16 + l16;
#pragma unroll
        for (int i = 0; i < 4; ++i) {
          int row = m0 + wm * 64 + mi * 16 + quad * 4 + i;
          if (row < M) Cp[(long)row * ldc + col] = acc[mi][ni][i];
        }
      }
  }
}

// ---------------- fused bmm1+LN1+bmm2+LN2, barrier-free ----------------
// 2 waves per block (grid = 2*N): block handles instance n = bid>>1,
// wave handles row-stripe (bid&1)*2 + waveid. launch_bounds(128,4) caps
// the unified VGPR+AGPR budget at 128/wave -> 4 waves/SIMD residency.
// f1 region overlays the first 1KB of the wave's C2 buffer (DS ops within
// a wave are in-order; af2 reads precede C2 writes in program order).
__global__ __launch_bounds__(128, 4) void bmm12_ln(
    const float* __restrict__ roi,  // (R, N, H) fp32
    const u16* __restrict__ P12,    // (N, 32768) bf16, frag layout
    const float* __restrict__ g1, const float* __restrict__ b1,
    const float* __restrict__ g2, const float* __restrict__ b2,
    u16* __restrict__ f2n)          // (N, R, H) bf16
{
  __shared__ u16 smem[2][16 * 264];  // per-wave 8448B
  const int bid = blockIdx.x;
  const int n = bid >> 1;
  const int waveid = threadIdx.x >> 6;
  const int stripe = (bid & 1) * 2 + waveid;
  const int lane = threadIdx.x & 63;
  const int quad = lane >> 4, l16 = lane & 15;
  const int wstripe = stripe * 16;
  u16* wsm = smem[waveid];
  const int lanebase = (l16 * 4 + quad) * 8;  // 16B unit within 1KB frag block

  const u16* P1f = P12 + (long)n * 32768;
  const u16* P2f = P1f + 16384;
  int r = wstripe + l16;
  int rr = (r < R_DIM) ? r : 0;
  const float* Arow = roi + ((long)rr * N_INST + n) * H_DIM + quad * 8;

  float gv1[4], bv1[4];
#pragma unroll
  for (int sub = 0; sub < 4; ++sub) {
    gv1[sub] = g1[sub * 16 + l16]; bv1[sub] = b1[sub * 16 + l16];
  }

  // ---- bmm1: pipelined global frag loads, no staging ----
  f32x4 acc1[4];
#pragma unroll
  for (int i = 0; i < 4; ++i) acc1[i] = f32x4{0.f, 0.f, 0.f, 0.f};
#pragma unroll
  for (int ks = 0; ks < 8; ++ks) {
    const float4* ap = (const float4*)(Arow + ks * 32);
    short8 af = pack8(ap[0], ap[1]);
#pragma unroll
    for (int sub = 0; sub < 4; ++sub) {
      short8 bf = ld8(P1f + (sub * 8 + ks) * 512 + lanebase);
      acc1[sub] = mfma16(af, bf, acc1[sub]);
    }
  }

  // ---- LN1 (quad-local, width-16 butterflies) -> f1 (wave-local LDS) ----
  {
    float s1[4], s2[4];
#pragma unroll
    for (int i = 0; i < 4; ++i) {
      s1[i] = 0.f; s2[i] = 0.f;
#pragma unroll
      for (int sub = 0; sub < 4; ++sub) {
        float v = acc1[sub][i]; s1[i] += v; s2[i] += v * v;
      }
    }
#pragma unroll
    for (int m = 1; m < 16; m <<= 1)
#pragma unroll
      for (int i = 0; i < 4; ++i) {
        s1[i] += __shfl_xor(s1[i], m, 16);
        s2[i] += __shfl_xor(s2[i], m, 16);
      }
#pragma unroll
    for (int i = 0; i < 4; ++i) {
      float mean = s1[i] * (1.f / 64.f);
      float var = s2[i] * (1.f / 64.f) - mean * mean;
      float rs = rsqrtf(var + LN_EPS);
      int lrow = quad * 4 + i;
#pragma unroll
      for (int sub = 0; sub < 4; ++sub) {
        float y = fmaxf((acc1[sub][i] - mean) * rs * gv1[sub] + bv1[sub], 0.f);
        int kc = (sub * 2 + (l16 >> 3)) ^ (lrow & 7);  // chunk swizzle
        wsm[lrow * 64 + kc * 8 + (l16 & 7)] = f2bf(y);
      }
    }
  }

  // ---- bmm2: A from f1 (wave-local), B = direct global frag loads ----
  short8 af2[2];
#pragma unroll
  for (int ks = 0; ks < 2; ++ks) {
    int c2 = (ks * 4 + quad) ^ (l16 & 7);
    af2[ks] = ld8(&wsm[l16 * 64 + c2 * 8]);
  }
  f32x4 acc2[16];
#pragma unroll
  for (int i = 0; i < 16; ++i) acc2[i] = f32x4{0.f, 0.f, 0.f, 0.f};
#pragma unroll
  for (int ks = 0; ks < 2; ++ks)
#pragma unroll
    for (int sub = 0; sub < 16; ++sub) {
      short8 bf = ld8(P2f + (sub * 2 + ks) * 512 + lanebase);
      acc2[sub] = mfma16(af2[ks], bf, acc2[sub]);
    }

  // ---- LN2 stats over H=256 ----
  float mean2[4], rs2[4];
  {
    float s1[4], s2[4];
#pragma unroll
    for (int i = 0; i < 4; ++i) {
      s1[i] = 0.f; s2[i] = 0.f;
#pragma unroll
      for (int sub = 0; sub < 16; ++sub) {
        float v = acc2[sub][i]; s1[i] += v; s2[i] += v * v;
      }
    }
#pragma unroll
    for (int m = 1; m < 16; m <<= 1)
#pragma unroll
      for (int i = 0; i < 4; ++i) {
        s1[i] += __shfl_xor(s1[i], m, 16);
        s2[i] += __shfl_xor(s2[i], m, 16);
      }
#pragma unroll
    for (int i = 0; i < 4; ++i) {
      mean2[i] = s1[i] * (1.f / 256.f);
      float var = s2[i] * (1.f / 256.f) - mean2[i] * mean2[i];
      rs2[i] = rsqrtf(var + LN_EPS);
    }
  }

  // ---- z -> wave-local C2 buffer (f1 region dead by program order) ----
#pragma unroll
  for (int i = 0; i < 4; ++i) {
    int lrow = quad * 4 + i;
    if (wstripe + lrow < R_DIM) {
#pragma unroll
      for (int sub = 0; sub < 16; ++sub)
        wsm[lrow * 264 + sub * 16 + l16] =
            f2bf((acc2[sub][i] - mean2[i]) * rs2[i]);
    }
  }

  // ---- epilogue: y = relu(z*g2+b2), 16B stores, wave-local rows ----
  u16* f2out = f2n + (long)n * (R_DIM * H_DIM);
  for (int t = lane; t < 16 * 32; t += 64) {
    int lrow = t >> 5, c = t & 31;
    int grow = wstripe + lrow;
    if (grow < R_DIM) {
      short8 z8 = ld8(&wsm[lrow * 264 + c * 8]);
      const float4* gp = (const float4*)(g2 + c * 8);
      const float4* bp = (const float4*)(b2 + c * 8);
      float4 ga = gp[0], gb = gp[1], ba = bp[0], bb = bp[1];
      short8 y;
      y[0] = (short)f2bf(fmaxf(bf2f((u16)z8[0]) * ga.x + ba.x, 0.f));
      y[1] = (short)f2bf(fmaxf(bf2f((u16)z8[1]) * ga.y + ba.y, 0.f));
      y[2] = (short)f2bf(fmaxf(bf2f((u16)z8[2]) * ga.z + ba.z, 0.f));
      y[3] = (short)f2bf(fmaxf(bf2f((u16)z8[3]) * ga.w + ba.w, 0.f));
      y[4] = (short)f2bf(fmaxf(bf2f((u16)z8[4]) * gb.x + bb.x, 0.f));
      y[5] = (short)f2bf(fmaxf(bf2f((u16)z8[5]) * gb.y + bb.y, 0.f));
      y[6] = (short)f2bf(fmaxf(bf2f((u16)z8[6]) * gb.z + bb.z, 0.f));
      y[7] = (short)f2bf(fmaxf(bf2f((u16)z8[7]) * gb.w + bb.w, 0.f));
      *reinterpret_cast<short8*>(f2out + grow * 256 + c * 8) = y;
    }
  }
}

// Sum split-K partials + bias, LN over H, ReLU -> fp32 out. One wave per row.
__global__ __launch_bounds__(64) void ln3_k(
    const float* __restrict__ partial,  // (SPLITK, N, H) fp32
    const float* __restrict__ b_out,
    const float* __restrict__ g3, const float* __restrict__ b3,
    float* __restrict__ out)            // (N, H) fp32
{
  const int n = blockIdx.x;
  const int lane = threadIdx.x;
  float x[4], sv = 0.f, s2 = 0.f;
#pragma unroll
  for (int j = 0; j < 4; ++j) {
    int h = lane + 64 * j;
    float v = b_out[h];
#pragma unroll
    for (int ss = 0; ss < SPLITK; ++ss)
      v += partial[((long)ss * N_INST + n) * H_DIM + h];
    x[j] = v; sv += v; s2 += v * v;
  }
  wave_reduce2(sv, s2);
  float mean = sv * (1.f / 256.f);
  float var = s2 * (1.f / 256.f) - mean * mean;
  float rs = rsqrtf(var + LN_EPS);
#pragma unroll
  for (int j = 0; j < 4; ++j) {
    int h = lane + 64 * j;
    float y = fmaxf((x[j] - mean) * rs * g3[h] + b3[h], 0.f);
    out[(long)n * H_DIM + h] = y;
  }
}

extern "C" void kernel_launch(void* const* d_in, const int* in_sizes, int n_in,
                              void* d_out, int out_size, void* d_ws, size_t ws_size,
                              hipStream_t stream) {
  const float* pro  = (const float*)d_in[0];
  const float* roi  = (const float*)d_in[1];
  const float* Wdyn = (const float*)d_in[2];
  const float* bdyn = (const float*)d_in[3];
  const float* Wout = (const float*)d_in[4];
  const float* bout = (const float*)d_in[5];
  const float* g1 = (const float*)d_in[6];
  const float* b1 = (const float*)d_in[7];
  const float* g2 = (const float*)d_in[8];
  const float* b2 = (const float*)d_in[9];
  const float* g3 = (const float*)d_in[10];
  const float* b3 = (const float*)d_in[11];
  float* out = (float*)d_out;

  // ws layout (bytes):
  //   proB  @ 0          : 1,024,000
  //   WdynT @ 1,024,000  : 16,777,216
  //   WoutT @ 17,801,216 : 6,422,528
  //   P12   @ 24,223,744 : 131,072,000 (frag layout; partial aliases)
  //   f2n   @ 155,295,744: 50,176,000
  char* ws = (char*)d_ws;
  u16* proB  = (u16*)ws;
  u16* WdynT = (u16*)(ws + 1024000);
  u16* WoutT = (u16*)(ws + 17801216);
  u16* P12   = (u16*)(ws + 24223744);
  u16* f2n   = (u16*)(ws + 155295744);
  float* partial = (float*)(ws + 24223744);

  dim3 blk(256);

  cast_pro<<<dim3(500), blk, 0, stream>>>(pro, proB, 512000 / 4);
  cast_wdyn<<<dim3(2048), blk, 0, stream>>>(Wdyn, WdynT);
  cast_wout<<<dim3(784), blk, 0, stream>>>(Wout, WoutT);

  // params: (2000x256)@(256x32768) -> P12 frag-native layout
  gemm128<<<dim3(16 * 256, 1), blk, 0, stream>>>(
      proB, H_DIM, N_INST, WdynT, H_DIM, bdyn,
      (void*)P12, 32768, 0L, 8, 256, 1);
  // fused bmm1+LN1+bmm2+LN2 (barrier-free, 2 waves/block)
  bmm12_ln<<<dim3(2 * N_INST), dim3(128), 0, stream>>>(
      roi, P12, g1, b1, g2, b2, f2n);
  // out GEMM: (2000x12544)@(12544x256), split-K=14 (28 ksteps)
  gemm128<<<dim3(16 * 2, SPLITK), blk, 0, stream>>>(
      f2n, R_DIM * H_DIM, N_INST, WoutT, R_DIM * H_DIM, nullptr,
      (void*)partial, H_DIM, (long)N_INST * H_DIM, 28, 2, 2);
  ln3_k<<<dim3(N_INST), dim3(64), 0, stream>>>(partial, bout, g3, b3, out);
}

// Round 9
// 342.868 us; speedup vs baseline: 1.0438x; 1.0438x over previous
//
#include <hip/hip_runtime.h>

typedef unsigned short u16;
typedef __attribute__((ext_vector_type(8))) short short8;
typedef __attribute__((ext_vector_type(4))) float f32x4;

#define N_INST 2000
#define H_DIM 256
#define D_DIM 64
#define R_DIM 49
#define LN_EPS 1e-5f
#define SPLITK 14

__device__ __forceinline__ u16 f2bf(float f) {
  union { float f; unsigned int i; } x; x.f = f;
  unsigned int r = x.i + 0x7fffu + ((x.i >> 16) & 1u);  // RNE
  return (u16)(r >> 16);
}
__device__ __forceinline__ float bf2f(u16 u) {
  union { unsigned int i; float f; } x; x.i = ((unsigned int)u) << 16; return x.f;
}
__device__ __forceinline__ short8 ld8(const u16* p) {
  return *reinterpret_cast<const short8*>(p);
}
__device__ __forceinline__ short8 pack8(float4 a, float4 b) {
  short8 r;
  r[0] = (short)f2bf(a.x); r[1] = (short)f2bf(a.y);
  r[2] = (short)f2bf(a.z); r[3] = (short)f2bf(a.w);
  r[4] = (short)f2bf(b.x); r[5] = (short)f2bf(b.y);
  r[6] = (short)f2bf(b.z); r[7] = (short)f2bf(b.w);
  return r;
}
__device__ __forceinline__ f32x4 mfma16(short8 a, short8 b, f32x4 c) {
  return __builtin_amdgcn_mfma_f32_16x16x32_bf16(a, b, c, 0, 0, 0);
}
__device__ __forceinline__ void wave_reduce2(float& s, float& s2) {
#pragma unroll
  for (int off = 32; off > 0; off >>= 1) {
    s  += __shfl_down(s, off);
    s2 += __shfl_down(s2, off);
  }
  s = __shfl(s, 0); s2 = __shfl(s2, 0);
}
__device__ __forceinline__ void gload16(const u16* g, u16* l) {
  __builtin_amdgcn_global_load_lds(
      (const __attribute__((address_space(1))) void*)g,
      (__attribute__((address_space(3))) void*)l, 16, 0, 0);
}

// ---------------- cast/transpose prep kernels ----------------
__global__ __launch_bounds__(256) void cast_pro(const float* __restrict__ in,
                                                u16* __restrict__ out, int n4) {
  for (int i = blockIdx.x * 256 + threadIdx.x; i < n4; i += gridDim.x * 256) {
    float4 v = ((const float4*)in)[i];
    u16* op = out + i * 4;
    op[0] = f2bf(v.x); op[1] = f2bf(v.y); op[2] = f2bf(v.z); op[3] = f2bf(v.w);
  }
}

// Wdyn (256 x 32768) fp32 -> WdynT bf16, transposed + permuted (both halves)
__global__ __launch_bounds__(256) void cast_wdyn(const float* __restrict__ W,
                                                 u16* __restrict__ WT) {
  __shared__ u16 T[64][65];
  const int tid = threadIdx.x;
  const int wave = tid >> 6, lane = tid & 63;
  const int half = blockIdx.x >> 10;
  const int b = blockIdx.x & 1023;
  const int kt = b >> 8;
  long colbase, rowbase; int rstride;
  if (half == 0) {
    int h = b & 255;
    colbase = (long)h * 64; rowbase = h; rstride = 256;
  } else {
    int d = b & 63, hc = (b >> 6) & 3;
    colbase = 16384L + d * 256 + hc * 64;
    rowbase = 16384L + hc * 4096 + d; rstride = 64;
  }
#pragma unroll
  for (int i = 0; i < 16; ++i) {
    int kk = wave * 16 + i;
    int k = kt * 64 + kk;
    T[kk][lane] = f2bf(W[(long)k * 32768 + colbase + lane]);
  }
  __syncthreads();
#pragma unroll
  for (int i = 0; i < 16; ++i) {
    int jj = wave * 16 + i;
    long ro = rowbase + (long)jj * rstride;
    WT[ro * 256 + kt * 64 + lane] = T[lane][jj];
  }
}

// Wout (12544 x 256) fp32 -> WoutT (256 x 12544) bf16
__global__ __launch_bounds__(256) void cast_wout(const float* __restrict__ W,
                                                 u16* __restrict__ WT) {
  __shared__ u16 T[64][65];
  const int tid = threadIdx.x;
  const int wave = tid >> 6, lane = tid & 63;
  const int kt = blockIdx.x >> 2, ct = blockIdx.x & 3;
#pragma unroll
  for (int i = 0; i < 16; ++i) {
    int kk = wave * 16 + i;
    long k = (long)kt * 64 + kk;
    T[kk][lane] = f2bf(W[k * 256 + ct * 64 + lane]);
  }
  __syncthreads();
#pragma unroll
  for (int i = 0; i < 16; ++i) {
    int cc = wave * 16 + i;
    long c = (long)ct * 64 + cc;
    WT[c * 12544 + (long)kt * 64 + lane] = T[lane][cc];
  }
}

// ---------------- 128x128 GEMM, double-buffered DMA staging ----------------
// cmode 1: bf16 store in MFMA-fragment-native P12 layout (+permuted bias).
// cmode 2: fp32 split-K partial at Cout + s*c_stride_s.
__global__ __launch_bounds__(256, 3) void gemm128(
    const u16* __restrict__ A, int lda, int M,
    const u16* __restrict__ BT, int ldbt,
    const float* __restrict__ bias,
    void* __restrict__ Cout, int ldc, long c_stride_s,
    int ksteps, int n_blocks, int cmode)
{
  union Smem {
    struct { u16 a[2][128 * 32]; u16 b[2][128 * 32]; } s;
    u16 cb[128 * 128];
  };
  __shared__ Smem sm;

  const int tid = threadIdx.x;
  const int wave = tid >> 6, lane = tid & 63;
  const int quad = lane >> 4, l16 = lane & 15;
  const int wm = wave >> 1, wn = wave & 1;
  const int bid = blockIdx.x;
  const int mblk = bid / n_blocks, nblk = bid - mblk * n_blocks;
  const int m0 = mblk * 128, n0 = nblk * 128;
  const int s = blockIdx.y;
  const int kb = s * ksteps * 32;

  const int cl = tid & 3;
  const int r0 = tid >> 2, r1 = 64 + (tid >> 2);
  const int cg0 = cl ^ ((r0 >> 1) & 3);
  const int cg1 = cl ^ ((r1 >> 1) & 3);
  int ga0 = m0 + r0; if (ga0 >= M) ga0 = M - 1;
  int ga1 = m0 + r1; if (ga1 >= M) ga1 = M - 1;
  const u16* gA0 = A + (long)ga0 * lda + kb + cg0 * 8;
  const u16* gA1 = A + (long)ga1 * lda + kb + cg1 * 8;
  const u16* gB0 = BT + (long)(n0 + r0) * ldbt + kb + cg0 * 8;
  const u16* gB1 = BT + (long)(n0 + r1) * ldbt + kb + cg1 * 8;

  int fAoff[4], fBoff[4];
#pragma unroll
  for (int i = 0; i < 4; ++i) {
    int rt = wm * 64 + i * 16 + l16;
    fAoff[i] = rt * 32 + (quad ^ ((rt >> 1) & 3)) * 8;
    int ct = wn * 64 + i * 16 + l16;
    fBoff[i] = ct * 32 + (quad ^ ((ct >> 1) & 3)) * 8;
  }

  f32x4 acc[4][4];
#pragma unroll
  for (int mi = 0; mi < 4; ++mi)
#pragma unroll
    for (int ni = 0; ni < 4; ++ni) acc[mi][ni] = f32x4{0.f, 0.f, 0.f, 0.f};

  gload16(gA0, &sm.s.a[0][tid * 8]);
  gload16(gA1, &sm.s.a[0][(tid + 256) * 8]);
  gload16(gB0, &sm.s.b[0][tid * 8]);
  gload16(gB1, &sm.s.b[0][(tid + 256) * 8]);

  for (int ks = 0; ks < ksteps; ++ks) {
    const int cur = ks & 1, nxt = cur ^ 1;
    __syncthreads();
    if (ks + 1 < ksteps) {
      const int ko = (ks + 1) * 32;
      gload16(gA0 + ko, &sm.s.a[nxt][tid * 8]);
      gload16(gA1 + ko, &sm.s.a[nxt][(tid + 256) * 8]);
      gload16(gB0 + ko, &sm.s.b[nxt][tid * 8]);
      gload16(gB1 + ko, &sm.s.b[nxt][(tid + 256) * 8]);
    }
    short8 av[4], bv[4];
#pragma unroll
    for (int i = 0; i < 4; ++i) {
      av[i] = ld8(&sm.s.a[cur][fAoff[i]]);
      bv[i] = ld8(&sm.s.b[cur][fBoff[i]]);
    }
#pragma unroll
    for (int mi = 0; mi < 4; ++mi)
#pragma unroll
      for (int ni = 0; ni < 4; ++ni)
        acc[mi][ni] = mfma16(av[mi], bv[ni], acc[mi][ni]);
  }

  if (cmode == 1) {
    float bvv[4];
#pragma unroll
    for (int ni = 0; ni < 4; ++ni) {
      int col = n0 + wn * 64 + ni * 16 + l16;
      int bi = (col < 16384) ? (((col & 255) << 6) + (col >> 8))
                             : (16384 + ((col & 63) << 8) + ((col >> 6) & 255));
      bvv[ni] = bias[bi];
    }
    __syncthreads();
#pragma unroll
    for (int mi = 0; mi < 4; ++mi)
#pragma unroll
      for (int ni = 0; ni < 4; ++ni)
#pragma unroll
        for (int i = 0; i < 4; ++i) {
          int row = wm * 64 + mi * 16 + quad * 4 + i;
          int col = wn * 64 + ni * 16 + l16;
          sm.cb[row * 128 + col] = f2bf(acc[mi][ni][i] + bvv[ni]);
        }
    __syncthreads();
    u16* Cp = (u16*)Cout;
#pragma unroll
    for (int j = 0; j < 8; ++j) {
      int lin = j * 2048 + tid * 8;
      int row = lin >> 7, col0 = n0 + (lin & 127);
      int grow = m0 + row;
      long toff;
      if (col0 < 16384) {
        int d = col0 >> 8, h = col0 & 255;
        toff = ((((d >> 4) * 8 + (h >> 5)) * 16 + (d & 15)) * 4 +
                ((h >> 3) & 3)) * 8;
      } else {
        int c2 = col0 - 16384;
        int h = c2 >> 6, d = c2 & 63;
        toff = 16384 + ((((h >> 4) * 2 + (d >> 5)) * 16 + (h & 15)) * 4 +
                        ((d >> 3) & 3)) * 8;
      }
      if (grow < M)
        *reinterpret_cast<short8*>(Cp + (long)grow * 32768 + toff) =
            ld8(&sm.cb[lin]);
    }
  } else {
    float* Cp = (float*)Cout + (long)s * c_stride_s;
#pragma unroll
    for (int mi = 0; mi < 4; ++mi)
#pragma unroll
      for (int ni = 0; ni < 4; ++ni) {
        int col = n0 + wn * 64 + ni * 16 + l16;
#pragma unroll
        for (int i = 0; i < 4; ++i) {
          int row = m0 + wm * 64 + mi * 16 + quad * 4 + i;
          if (row < M) Cp[(long)row * ldc + col] = acc[mi][ni][i];
        }
      }
  }
}

// ---------------- fused bmm1+LN1+bmm2+LN2, barrier-free ----------------
// One block per instance, 4 waves, wave = 16-row stripe. bmm2 runs in TWO
// half-H phases of 8 sub-tiles (32 AGPRs instead of 64): raw x spilled bf16
// to the wave-local LDS buffer, LN2 applied at readback. Per-wave LDS:
// 16x264 x-buffer (f1 overlays first 1KB; safe: af2 read before any x write)
// + 32 floats of per-row mean/rs. Zero __syncthreads.
__global__ __launch_bounds__(256, 4) void bmm12_ln(
    const float* __restrict__ roi,  // (R, N, H) fp32
    const u16* __restrict__ P12,    // (N, 32768) bf16, frag layout
    const float* __restrict__ g1, const float* __restrict__ b1,
    const float* __restrict__ g2, const float* __restrict__ b2,
    u16* __restrict__ f2n)          // (N, R, H) bf16
{
  __shared__ u16 smem[4][16 * 264 + 64];  // per-wave 8576 B
  const int n = blockIdx.x;
  const int wave = threadIdx.x >> 6;
  const int lane = threadIdx.x & 63;
  const int quad = lane >> 4, l16 = lane & 15;
  const int wstripe = wave * 16;
  u16* wsm = smem[wave];
  float* wstat = (float*)(wsm + 16 * 264);  // [0..15]=mean, [16..31]=rs
  const int lanebase = (l16 * 4 + quad) * 8;

  const u16* P1f = P12 + (long)n * 32768;
  const u16* P2f = P1f + 16384;
  int r = wstripe + l16;
  int rr = (r < R_DIM) ? r : 0;
  const float* Arow = roi + ((long)rr * N_INST + n) * H_DIM + quad * 8;

  float gv1[4], bv1[4];
#pragma unroll
  for (int sub = 0; sub < 4; ++sub) {
    gv1[sub] = g1[sub * 16 + l16]; bv1[sub] = b1[sub * 16 + l16];
  }

  // ---- bmm1: direct global frag loads, no staging ----
  f32x4 acc1[4];
#pragma unroll
  for (int i = 0; i < 4; ++i) acc1[i] = f32x4{0.f, 0.f, 0.f, 0.f};
#pragma unroll
  for (int ks = 0; ks < 8; ++ks) {
    const float4* ap = (const float4*)(Arow + ks * 32);
    short8 af = pack8(ap[0], ap[1]);
#pragma unroll
    for (int sub = 0; sub < 4; ++sub) {
      short8 bf = ld8(P1f + (sub * 8 + ks) * 512 + lanebase);
      acc1[sub] = mfma16(af, bf, acc1[sub]);
    }
  }

  // ---- LN1 (quad-local butterflies) -> f1 (first 1KB of wsm) ----
  {
    float s1[4], s2[4];
#pragma unroll
    for (int i = 0; i < 4; ++i) {
      s1[i] = 0.f; s2[i] = 0.f;
#pragma unroll
      for (int sub = 0; sub < 4; ++sub) {
        float v = acc1[sub][i]; s1[i] += v; s2[i] += v * v;
      }
    }
#pragma unroll
    for (int m = 1; m < 16; m <<= 1)
#pragma unroll
      for (int i = 0; i < 4; ++i) {
        s1[i] += __shfl_xor(s1[i], m, 16);
        s2[i] += __shfl_xor(s2[i], m, 16);
      }
#pragma unroll
    for (int i = 0; i < 4; ++i) {
      float mean = s1[i] * (1.f / 64.f);
      float var = s2[i] * (1.f / 64.f) - mean * mean;
      float rs = rsqrtf(var + LN_EPS);
      int lrow = quad * 4 + i;
#pragma unroll
      for (int sub = 0; sub < 4; ++sub) {
        float y = fmaxf((acc1[sub][i] - mean) * rs * gv1[sub] + bv1[sub], 0.f);
        int kc = (sub * 2 + (l16 >> 3)) ^ (lrow & 7);
        wsm[lrow * 64 + kc * 8 + (l16 & 7)] = f2bf(y);
      }
    }
  }

  // ---- read A-frags for bmm2 BEFORE any x-spill overwrites f1 ----
  short8 af2[2];
#pragma unroll
  for (int ks = 0; ks < 2; ++ks) {
    int c2 = (ks * 4 + quad) ^ (l16 & 7);
    af2[ks] = ld8(&wsm[l16 * 64 + c2 * 8]);
  }

  // ---- bmm2 in two half-H phases: 8 sub-tiles (32 AGPRs) each ----
  float s1[4], s2[4];
#pragma unroll
  for (int i = 0; i < 4; ++i) { s1[i] = 0.f; s2[i] = 0.f; }
#pragma unroll
  for (int ph = 0; ph < 2; ++ph) {
    f32x4 acc2[8];
#pragma unroll
    for (int i = 0; i < 8; ++i) acc2[i] = f32x4{0.f, 0.f, 0.f, 0.f};
#pragma unroll
    for (int ks = 0; ks < 2; ++ks)
#pragma unroll
      for (int sub = 0; sub < 8; ++sub) {
        short8 bf = ld8(P2f + ((ph * 8 + sub) * 2 + ks) * 512 + lanebase);
        acc2[sub] = mfma16(af2[ks], bf, acc2[sub]);
      }
    // spill raw x (bf16) + accumulate stats
#pragma unroll
    for (int i = 0; i < 4; ++i) {
      int lrow = quad * 4 + i;
#pragma unroll
      for (int sub = 0; sub < 8; ++sub) {
        float v = acc2[sub][i];
        s1[i] += v; s2[i] += v * v;
        wsm[lrow * 264 + (ph * 8 + sub) * 16 + l16] = f2bf(v);
      }
    }
  }

  // ---- LN2 stats over H=256, park per-row mean/rs in LDS ----
  {
#pragma unroll
    for (int m = 1; m < 16; m <<= 1)
#pragma unroll
      for (int i = 0; i < 4; ++i) {
        s1[i] += __shfl_xor(s1[i], m, 16);
        s2[i] += __shfl_xor(s2[i], m, 16);
      }
    if (l16 == 0) {
#pragma unroll
      for (int i = 0; i < 4; ++i) {
        int lrow = quad * 4 + i;
        float mean = s1[i] * (1.f / 256.f);
        float var = s2[i] * (1.f / 256.f) - mean * mean;
        wstat[lrow] = mean;
        wstat[16 + lrow] = rsqrtf(var + LN_EPS);
      }
    }
  }

  // ---- epilogue: y = relu((x-mean)*rs*g2+b2), 16B stores, wave-local ----
  u16* f2out = f2n + (long)n * (R_DIM * H_DIM);
  for (int t = lane; t < 16 * 32; t += 64) {
    int lrow = t >> 5, c = t & 31;
    int grow = wstripe + lrow;
    if (grow < R_DIM) {
      short8 x8 = ld8(&wsm[lrow * 264 + c * 8]);
      float mean = wstat[lrow], rs = wstat[16 + lrow];
      const float4* gp = (const float4*)(g2 + c * 8);
      const float4* bp = (const float4*)(b2 + c * 8);
      float4 ga = gp[0], gb = gp[1], ba = bp[0], bb = bp[1];
      short8 y;
      y[0] = (short)f2bf(fmaxf((bf2f((u16)x8[0]) - mean) * rs * ga.x + ba.x, 0.f));
      y[1] = (short)f2bf(fmaxf((bf2f((u16)x8[1]) - mean) * rs * ga.y + ba.y, 0.f));
      y[2] = (short)f2bf(fmaxf((bf2f((u16)x8[2]) - mean) * rs * ga.z + ba.z, 0.f));
      y[3] = (short)f2bf(fmaxf((bf2f((u16)x8[3]) - mean) * rs * ga.w + ba.w, 0.f));
      y[4] = (short)f2bf(fmaxf((bf2f((u16)x8[4]) - mean) * rs * gb.x + bb.x, 0.f));
      y[5] = (short)f2bf(fmaxf((bf2f((u16)x8[5]) - mean) * rs * gb.y + bb.y, 0.f));
      y[6] = (short)f2bf(fmaxf((bf2f((u16)x8[6]) - mean) * rs * gb.z + bb.z, 0.f));
      y[7] = (short)f2bf(fmaxf((bf2f((u16)x8[7]) - mean) * rs * gb.w + bb.w, 0.f));
      *reinterpret_cast<short8*>(f2out + grow * 256 + c * 8) = y;
    }
  }
}

// Sum split-K partials + bias, LN over H, ReLU -> fp32 out. One wave per row.
__global__ __launch_bounds__(64) void ln3_k(
    const float* __restrict__ partial,  // (SPLITK, N, H) fp32
    const float* __restrict__ b_out,
    const float* __restrict__ g3, const float* __restrict__ b3,
    float* __restrict__ out)            // (N, H) fp32
{
  const int n = blockIdx.x;
  const int lane = threadIdx.x;
  float x[4], sv = 0.f, s2 = 0.f;
#pragma unroll
  for (int j = 0; j < 4; ++j) {
    int h = lane + 64 * j;
    float v = b_out[h];
#pragma unroll
    for (int ss = 0; ss < SPLITK; ++ss)
      v += partial[((long)ss * N_INST + n) * H_DIM + h];
    x[j] = v; sv += v; s2 += v * v;
  }
  wave_reduce2(sv, s2);
  float mean = sv * (1.f / 256.f);
  float var = s2 * (1.f / 256.f) - mean * mean;
  float rs = rsqrtf(var + LN_EPS);
#pragma unroll
  for (int j = 0; j < 4; ++j) {
    int h = lane + 64 * j;
    float y = fmaxf((x[j] - mean) * rs * g3[h] + b3[h], 0.f);
    out[(long)n * H_DIM + h] = y;
  }
}

extern "C" void kernel_launch(void* const* d_in, const int* in_sizes, int n_in,
                              void* d_out, int out_size, void* d_ws, size_t ws_size,
                              hipStream_t stream) {
  const float* pro  = (const float*)d_in[0];
  const float* roi  = (const float*)d_in[1];
  const float* Wdyn = (const float*)d_in[2];
  const float* bdyn = (const float*)d_in[3];
  const float* Wout = (const float*)d_in[4];
  const float* bout = (const float*)d_in[5];
  const float* g1 = (const float*)d_in[6];
  const float* b1 = (const float*)d_in[7];
  const float* g2 = (const float*)d_in[8];
  const float* b2 = (const float*)d_in[9];
  const float* g3 = (const float*)d_in[10];
  const float* b3 = (const float*)d_in[11];
  float* out = (float*)d_out;

  // ws layout (bytes):
  //   proB  @ 0          : 1,024,000
  //   WdynT @ 1,024,000  : 16,777,216
  //   WoutT @ 17,801,216 : 6,422,528
  //   P12   @ 24,223,744 : 131,072,000 (frag layout; partial aliases)
  //   f2n   @ 155,295,744: 50,176,000
  char* ws = (char*)d_ws;
  u16* proB  = (u16*)ws;
  u16* WdynT = (u16*)(ws + 1024000);
  u16* WoutT = (u16*)(ws + 17801216);
  u16* P12   = (u16*)(ws + 24223744);
  u16* f2n   = (u16*)(ws + 155295744);
  float* partial = (float*)(ws + 24223744);

  dim3 blk(256);

  cast_pro<<<dim3(500), blk, 0, stream>>>(pro, proB, 512000 / 4);
  cast_wdyn<<<dim3(2048), blk, 0, stream>>>(Wdyn, WdynT);
  cast_wout<<<dim3(784), blk, 0, stream>>>(Wout, WoutT);

  // params: (2000x256)@(256x32768) -> P12 frag-native layout
  gemm128<<<dim3(16 * 256, 1), blk, 0, stream>>>(
      proB, H_DIM, N_INST, WdynT, H_DIM, bdyn,
      (void*)P12, 32768, 0L, 8, 256, 1);
  // fused bmm1+LN1+bmm2+LN2 (barrier-free, 1 block/instance, 4 waves)
  bmm12_ln<<<dim3(N_INST), blk, 0, stream>>>(
      roi, P12, g1, b1, g2, b2, f2n);
  // out GEMM: (2000x12544)@(12544x256), split-K=14 (28 ksteps)
  gemm128<<<dim3(16 * 2, SPLITK), blk, 0, stream>>>(
      f2n, R_DIM * H_DIM, N_INST, WoutT, R_DIM * H_DIM, nullptr,
      (void*)partial, H_DIM, (long)N_INST * H_DIM, 28, 2, 2);
  ln3_k<<<dim3(N_INST), dim3(64), 0, stream>>>(partial, bout, g3, b3, out);
}